// Round 1
// baseline (1120.601 us; speedup 1.0000x reference)
//
#include <hip/hip_runtime.h>
#include <hip/hip_bf16.h>

#define B_ 8
#define C_ 256
#define H_ 128
#define W_ 128
#define HW_ 16384
#define CHW_ (C_ * HW_)
#define NH_ 8
#define HD_ 32
#define NTOT (B_ * CHW_)   // 33,554,432

// ---------------- depthwise 3x3 conv (SAME, cross-correlation) ----------------
__global__ __launch_bounds__(256) void dw_conv_kernel(const float* __restrict__ x,
                                                      const float* __restrict__ dww,
                                                      float* __restrict__ hdw) {
    int idx = blockIdx.x * 256 + threadIdx.x;
    int p = idx & (HW_ - 1);
    int c = (idx >> 14) & 255;
    int b = idx >> 22;
    int h = p >> 7, w = p & 127;
    const float* xb = x + ((size_t)b * C_ + c) * HW_;
    const float* wt = dww + c * 9;
    float s = 0.f;
#pragma unroll
    for (int ky = 0; ky < 3; ++ky) {
        int hh = h + ky - 1;
        if (hh < 0 || hh > H_ - 1) continue;
#pragma unroll
        for (int kx = 0; kx < 3; ++kx) {
            int ww = w + kx - 1;
            if (ww < 0 || ww > W_ - 1) continue;
            s += xb[hh * W_ + ww] * wt[ky * 3 + kx];
        }
    }
    hdw[idx] = s;
}

// ---------------- offset projection 256 -> 16, tanh*0.5 ----------------
__global__ __launch_bounds__(256) void offset_kernel(const float* __restrict__ hdw,
                                                     const float* __restrict__ offw,
                                                     const float* __restrict__ offb,
                                                     float* __restrict__ offout) {
    __shared__ float wT[256][16];   // [c][o], 16 KB
    __shared__ float bsh[16];
    int tid = threadIdx.x;
    for (int i = tid; i < 4096; i += 256) {
        int o = i >> 8, c = i & 255;
        wT[c][o] = offw[i];  // offw is [o][c] row-major, i = o*256+c
    }
    if (tid < 16) bsh[tid] = offb[tid];
    __syncthreads();
    int gp = blockIdx.x * 256 + tid;       // (b, pix)
    int b = gp >> 14, pix = gp & (HW_ - 1);
    const float* hb = hdw + (size_t)b * CHW_ + pix;
    float acc[16] = {};
    for (int c = 0; c < 256; ++c) {
        float v = hb[(size_t)c * HW_];
#pragma unroll
        for (int o = 0; o < 16; ++o) acc[o] += v * wT[c][o];
    }
    float* ob = offout + (size_t)b * 16 * HW_ + pix;
#pragma unroll
    for (int o = 0; o < 16; ++o)
        ob[(size_t)o * HW_] = tanhf(acc[o] + bsh[o]) * 0.5f;
}

// ---------------- fp32 GEMM: Y[b] (256 x HW) = Wmat (256x256) * X[b] (256 x HW) ----------------
// 128x128 tile, BK=8, 256 threads, 8x8 per thread.
#define BM 128
#define BN 128
#define BK 8
__global__ __launch_bounds__(256) void gemm_kernel(const float* __restrict__ Wmat,
                                                   const float* __restrict__ Xin,
                                                   float* __restrict__ Yout) {
    __shared__ float As[BK][BM];
    __shared__ float Bs[BK][BN];
    const int tid = threadIdx.x;
    const int b = blockIdx.z;
    const int m0 = blockIdx.y * BM;
    const int n0 = blockIdx.x * BN;
    const float* Xb = Xin + (size_t)b * CHW_;
    float* Yb = Yout + (size_t)b * CHW_;
    const int tx = tid & 15;   // n-group
    const int ty = tid >> 4;   // m-group
    const int a_m = tid >> 1;          // 0..127
    const int a_k = (tid & 1) * 4;     // 0 or 4
    const int b_k = tid >> 5;          // 0..7
    const int b_n = (tid & 31) * 4;    // 0..124
    float acc[8][8] = {};
    for (int k0 = 0; k0 < 256; k0 += BK) {
        float4 av = *(const float4*)&Wmat[(m0 + a_m) * 256 + k0 + a_k];
        float4 bv = *(const float4*)&Xb[(size_t)(k0 + b_k) * HW_ + n0 + b_n];
        __syncthreads();   // previous tile fully consumed
        As[a_k + 0][a_m] = av.x;
        As[a_k + 1][a_m] = av.y;
        As[a_k + 2][a_m] = av.z;
        As[a_k + 3][a_m] = av.w;
        *(float4*)&Bs[b_k][b_n] = bv;
        __syncthreads();
#pragma unroll
        for (int kk = 0; kk < BK; ++kk) {
            float4 a0 = *(const float4*)&As[kk][ty * 8];
            float4 a1 = *(const float4*)&As[kk][ty * 8 + 4];
            float4 b0 = *(const float4*)&Bs[kk][tx * 8];
            float4 b1 = *(const float4*)&Bs[kk][tx * 8 + 4];
            float a_[8] = {a0.x, a0.y, a0.z, a0.w, a1.x, a1.y, a1.z, a1.w};
            float b_[8] = {b0.x, b0.y, b0.z, b0.w, b1.x, b1.y, b1.z, b1.w};
#pragma unroll
            for (int i = 0; i < 8; ++i)
#pragma unroll
                for (int j = 0; j < 8; ++j) acc[i][j] += a_[i] * b_[j];
        }
    }
#pragma unroll
    for (int i = 0; i < 8; ++i) {
        int m = m0 + ty * 8 + i;
        float* yrow = Yb + (size_t)m * HW_ + n0 + tx * 8;
        *(float4*)&yrow[0] = make_float4(acc[i][0], acc[i][1], acc[i][2], acc[i][3]);
        *(float4*)&yrow[4] = make_float4(acc[i][4], acc[i][5], acc[i][6], acc[i][7]);
    }
}

// ---------------- bilinear deformable sampling ----------------
__global__ __launch_bounds__(256) void sample_kernel(const float* __restrict__ V,
                                                     const float* __restrict__ off,
                                                     float* __restrict__ out) {
    int idx = blockIdx.x * 256 + threadIdx.x;
    int p = idx & (HW_ - 1);
    int c = (idx >> 14) & 255;
    int b = idx >> 22;
    int head = c >> 5;
    int h = p >> 7, w = p & 127;
    const float* ob = off + (size_t)(b * 16 + head * 2) * HW_ + p;
    float dy = ob[0];
    float dx = ob[HW_];
    float gy = h * (2.0f / 127.0f) - 1.0f;
    float gx = w * (2.0f / 127.0f) - 1.0f;
    float sx = fminf(fmaxf(gx + dx, -1.0f), 1.0f);
    float sy = fminf(fmaxf(gy + dy, -1.0f), 1.0f);
    float ix = (sx + 1.0f) * 0.5f * 127.0f;
    float iy = (sy + 1.0f) * 0.5f * 127.0f;
    float x0f = floorf(ix), y0f = floorf(iy);
    float wx = ix - x0f, wy = iy - y0f;
    int x0 = min(max((int)x0f, 0), 127);
    int x1 = min((int)x0f + 1, 127);
    int y0 = min(max((int)y0f, 0), 127);
    int y1 = min((int)y0f + 1, 127);
    const float* Vb = V + ((size_t)b * C_ + c) * HW_;
    float v00 = Vb[y0 * W_ + x0];
    float v01 = Vb[y0 * W_ + x1];
    float v10 = Vb[y1 * W_ + x0];
    float v11 = Vb[y1 * W_ + x1];
    float s = v00 * (1.f - wx) * (1.f - wy) + v01 * wx * (1.f - wy) +
              v10 * (1.f - wx) * wy + v11 * wx * wy;
    out[idx] = s;
}

// ---------------- group sum / sumsq (per (b, head), 524288 elems each) ----------------
__global__ __launch_bounds__(256) void reduce_kernel(const float* __restrict__ g,
                                                     float* __restrict__ stats) {
    int blk = blockIdx.x;   // 64 groups * 16 sub-blocks
    int grp = blk >> 4;
    int sub = blk & 15;
    const float* base = g + (size_t)grp * (HD_ * HW_) + (size_t)sub * 32768;
    float s1 = 0.f, s2 = 0.f;
    for (int i = threadIdx.x * 4; i < 32768; i += 1024) {
        float4 v = *(const float4*)&base[i];
        s1 += v.x + v.y + v.z + v.w;
        s2 += v.x * v.x + v.y * v.y + v.z * v.z + v.w * v.w;
    }
#pragma unroll
    for (int o = 32; o; o >>= 1) {
        s1 += __shfl_down(s1, o);
        s2 += __shfl_down(s2, o);
    }
    __shared__ float ls1[4], ls2[4];
    int wave = threadIdx.x >> 6, lane = threadIdx.x & 63;
    if (lane == 0) { ls1[wave] = s1; ls2[wave] = s2; }
    __syncthreads();
    if (threadIdx.x == 0) {
        atomicAdd(&stats[grp * 2 + 0], ls1[0] + ls1[1] + ls1[2] + ls1[3]);
        atomicAdd(&stats[grp * 2 + 1], ls2[0] + ls2[1] + ls2[2] + ls2[3]);
    }
}

// ---------------- normalize + affine + residual ----------------
__global__ __launch_bounds__(256) void final_kernel(const float* __restrict__ x,
                                                    const float* __restrict__ stats,
                                                    const float* __restrict__ gamma,
                                                    const float* __restrict__ beta,
                                                    float* __restrict__ out) {
    int idx = blockIdx.x * 256 + threadIdx.x;
    int c = (idx >> 14) & 255;
    int b = idx >> 22;
    int grp = b * NH_ + (c >> 5);
    const float invN = 1.0f / (float)(HD_ * HW_);
    float mu = stats[grp * 2 + 0] * invN;
    float var = stats[grp * 2 + 1] * invN - mu * mu;
    float r = rsqrtf(var + 1e-5f);
    float v = out[idx];
    out[idx] = x[idx] + (v - mu) * r * gamma[c] + beta[c];
}

extern "C" void kernel_launch(void* const* d_in, const int* in_sizes, int n_in,
                              void* d_out, int out_size, void* d_ws, size_t ws_size,
                              hipStream_t stream) {
    const float* x     = (const float*)d_in[0];
    const float* dww   = (const float*)d_in[1];
    const float* offw  = (const float*)d_in[2];
    const float* offb  = (const float*)d_in[3];
    const float* vw    = (const float*)d_in[4];
    const float* ow    = (const float*)d_in[5];
    const float* gamma = (const float*)d_in[6];
    const float* beta  = (const float*)d_in[7];
    float* out = (float*)d_out;
    float* ws = (float*)d_ws;

    float* off_buf = ws;                 // 2,097,152 floats (8.4 MB)
    float* stats   = ws + 2097152;       // 128 floats
    float* slot1   = ws + 4194304;       // 33,554,432 floats (hdw, then sampled)

    // 1. depthwise conv -> slot1
    dw_conv_kernel<<<NTOT / 256, 256, 0, stream>>>(x, dww, slot1);
    // 2. offsets -> off_buf
    offset_kernel<<<(B_ * HW_) / 256, 256, 0, stream>>>(slot1, offw, offb, off_buf);
    // 3. V projection -> d_out (staging)
    gemm_kernel<<<dim3(HW_ / BN, C_ / BM, B_), 256, 0, stream>>>(vw, x, out);
    // 4. deformable bilinear sampling -> slot1 (hdw dead)
    sample_kernel<<<NTOT / 256, 256, 0, stream>>>(out, off_buf, slot1);
    // 5. O projection -> d_out (V dead)
    gemm_kernel<<<dim3(HW_ / BN, C_ / BM, B_), 256, 0, stream>>>(ow, slot1, out);
    // 6. group stats
    hipMemsetAsync(stats, 0, 128 * sizeof(float), stream);
    reduce_kernel<<<1024, 256, 0, stream>>>(out, stats);
    // 7. normalize + residual -> d_out
    final_kernel<<<NTOT / 256, 256, 0, stream>>>(x, stats, gamma, beta, out);
}